// Round 1
// baseline (296.344 us; speedup 1.0000x reference)
//
#include <hip/hip_runtime.h>
#include <hip/hip_bf16.h>

#define NCELL 64
#define CIN 8
#define EE 4
#define DD 4
#define HH 256
#define WW 256

#define TW 32
#define TH 16
#define ZW (TW + 4)   // 36
#define ZH (TH + 4)   // 20
#define HW1 (TW + 2)  // 34
#define HH1 (TH + 2)  // 18
#define NCG 4         // cells per block in edge pass

__device__ __forceinline__ float silu(float v) {
    return v / (1.0f + __expf(-v));
}

__global__ __launch_bounds__(256) void zero_kernel(float* __restrict__ p) {
    // zero EE*HH*WW floats = 65536 float4
    int i = blockIdx.x * 256 + threadIdx.x;
    reinterpret_cast<float4*>(p)[i] = make_float4(0.f, 0.f, 0.f, 0.f);
}

__global__ __launch_bounds__(256) void edge_kernel(
    const float* __restrict__ x,
    const float* __restrict__ w_down, const float* __restrict__ b_down,
    const float* __restrict__ w_e1, const float* __restrict__ b_e1,
    const float* __restrict__ w_e2, const float* __restrict__ b_e2,
    float* __restrict__ A)
{
    __shared__ float zb[EE][ZH][ZW];
    __shared__ float h1b[EE][HH1][HW1];

    const int tid = threadIdx.x;
    const int ox = blockIdx.x * TW;
    const int oy = blockIdx.y * TH;
    const int n0 = blockIdx.z * NCG;

    float acc[2][EE];
#pragma unroll
    for (int k = 0; k < 2; ++k)
#pragma unroll
        for (int e = 0; e < EE; ++e) acc[k][e] = 0.f;

    for (int j = 0; j < NCG; ++j) {
        const int n = n0 + j;
        const float* __restrict__ xn = x + (size_t)n * CIN * HH * WW;

        // ---- z = 1x1 conv (down) over halo-2 region ----
        for (int idx = tid; idx < ZH * ZW; idx += 256) {
            const int ly = idx / ZW, lx = idx % ZW;
            const int gy = oy + ly - 2, gx = ox + lx - 2;
            float zv[EE];
            if ((unsigned)gy < (unsigned)HH && (unsigned)gx < (unsigned)WW) {
                float xv[CIN];
#pragma unroll
                for (int c = 0; c < CIN; ++c)
                    xv[c] = xn[(c * HH + gy) * WW + gx];
#pragma unroll
                for (int e = 0; e < EE; ++e) {
                    float s = b_down[e];
#pragma unroll
                    for (int c = 0; c < CIN; ++c) s += xv[c] * w_down[e * CIN + c];
                    zv[e] = s;
                }
            } else {
#pragma unroll
                for (int e = 0; e < EE; ++e) zv[e] = 0.f;
            }
#pragma unroll
            for (int e = 0; e < EE; ++e) zb[e][ly][lx] = zv[e];
        }
        __syncthreads();

        // ---- h1 = silu(3x3 conv e1) over halo-1 region ----
        for (int idx = tid; idx < HH1 * HW1; idx += 256) {
            const int ly = idx / HW1, lx = idx % HW1;
            const int gy = oy + ly - 1, gx = ox + lx - 1;
            float hv[EE];
            if ((unsigned)gy < (unsigned)HH && (unsigned)gx < (unsigned)WW) {
                float s[EE];
#pragma unroll
                for (int o = 0; o < EE; ++o) s[o] = b_e1[o];
#pragma unroll
                for (int i = 0; i < EE; ++i)
#pragma unroll
                    for (int dy = 0; dy < 3; ++dy)
#pragma unroll
                        for (int dx = 0; dx < 3; ++dx) {
                            const float a = zb[i][ly + dy][lx + dx];
#pragma unroll
                            for (int o = 0; o < EE; ++o)
                                s[o] += a * w_e1[o * 36 + i * 9 + dy * 3 + dx];
                        }
#pragma unroll
                for (int o = 0; o < EE; ++o) hv[o] = silu(s[o]);
            } else {
#pragma unroll
                for (int o = 0; o < EE; ++o) hv[o] = 0.f;
            }
#pragma unroll
            for (int o = 0; o < EE; ++o) h1b[o][ly][lx] = hv[o];
        }
        __syncthreads();

        // ---- h2 = silu(3x3 conv e2), accumulate into acc ----
#pragma unroll
        for (int k = 0; k < 2; ++k) {
            const int idx = tid + k * 256;
            const int py = idx / TW, px = idx % TW;
            float s[EE];
#pragma unroll
            for (int o = 0; o < EE; ++o) s[o] = b_e2[o];
#pragma unroll
            for (int i = 0; i < EE; ++i)
#pragma unroll
                for (int dy = 0; dy < 3; ++dy)
#pragma unroll
                    for (int dx = 0; dx < 3; ++dx) {
                        const float a = h1b[i][py + dy][px + dx];
#pragma unroll
                        for (int o = 0; o < EE; ++o)
                            s[o] += a * w_e2[o * 36 + i * 9 + dy * 3 + dx];
                    }
#pragma unroll
            for (int o = 0; o < EE; ++o) acc[k][o] += silu(s[o]);
        }
        __syncthreads();
    }

    // ---- atomic accumulate into A ----
#pragma unroll
    for (int k = 0; k < 2; ++k) {
        const int idx = tid + k * 256;
        const int py = idx / TW, px = idx % TW;
        const int gy = oy + py, gx = ox + px;
#pragma unroll
        for (int e = 0; e < EE; ++e)
            atomicAdd(&A[(e * HH + gy) * WW + gx], acc[k][e]);
    }
}

__global__ __launch_bounds__(256) void up_kernel(
    const float* __restrict__ A,
    const float* __restrict__ w_up, const float* __restrict__ b_up,
    float* __restrict__ Aup)
{
    const int p = blockIdx.x * 256 + threadIdx.x;  // < HH*WW
    float a[EE];
#pragma unroll
    for (int e = 0; e < EE; ++e) a[e] = A[e * (HH * WW) + p];
#pragma unroll
    for (int c = 0; c < EE; ++c) {
        float s = b_up[c];
#pragma unroll
        for (int e = 0; e < EE; ++e) s += a[e] * w_up[c * EE + e];
        Aup[c * (HH * WW) + p] = s;
    }
}

__global__ __launch_bounds__(256) void node_kernel(
    const float* __restrict__ x, const float* __restrict__ Aup,
    const float* __restrict__ w_n1, const float* __restrict__ b_n1,
    const float* __restrict__ w_n2, const float* __restrict__ b_n2,
    const float* __restrict__ w_r, const float* __restrict__ b_r,
    float* __restrict__ out)
{
    __shared__ float xa[CIN + EE][ZH][ZW];  // 12 x 20 x 36
    __shared__ float y1b[DD][HH1][HW1];     // 4 x 18 x 34

    const int tid = threadIdx.x;
    const int ox = blockIdx.x * TW;
    const int oy = blockIdx.y * TH;
    const int n = blockIdx.z;
    const float* __restrict__ xn = x + (size_t)n * CIN * HH * WW;

    // ---- stage [x || Aup] tile with halo 2 ----
    for (int idx = tid; idx < ZH * ZW; idx += 256) {
        const int ly = idx / ZW, lx = idx % ZW;
        const int gy = oy + ly - 2, gx = ox + lx - 2;
        if ((unsigned)gy < (unsigned)HH && (unsigned)gx < (unsigned)WW) {
#pragma unroll
            for (int c = 0; c < CIN; ++c)
                xa[c][ly][lx] = xn[(c * HH + gy) * WW + gx];
#pragma unroll
            for (int e = 0; e < EE; ++e)
                xa[CIN + e][ly][lx] = Aup[(e * HH + gy) * WW + gx];
        } else {
#pragma unroll
            for (int c = 0; c < CIN + EE; ++c) xa[c][ly][lx] = 0.f;
        }
    }
    __syncthreads();

    // ---- y1 = silu(3x3 conv n1, 12->4) over halo-1 region ----
    for (int idx = tid; idx < HH1 * HW1; idx += 256) {
        const int ly = idx / HW1, lx = idx % HW1;
        const int gy = oy + ly - 1, gx = ox + lx - 1;
        float yv[DD];
        if ((unsigned)gy < (unsigned)HH && (unsigned)gx < (unsigned)WW) {
            float s[DD];
#pragma unroll
            for (int o = 0; o < DD; ++o) s[o] = b_n1[o];
#pragma unroll
            for (int i = 0; i < CIN + EE; ++i)
#pragma unroll
                for (int dy = 0; dy < 3; ++dy)
#pragma unroll
                    for (int dx = 0; dx < 3; ++dx) {
                        const float a = xa[i][ly + dy][lx + dx];
#pragma unroll
                        for (int o = 0; o < DD; ++o)
                            s[o] += a * w_n1[o * 108 + i * 9 + dy * 3 + dx];
                    }
#pragma unroll
            for (int o = 0; o < DD; ++o) yv[o] = silu(s[o]);
        } else {
#pragma unroll
            for (int o = 0; o < DD; ++o) yv[o] = 0.f;
        }
#pragma unroll
        for (int o = 0; o < DD; ++o) y1b[o][ly][lx] = yv[o];
    }
    __syncthreads();

    // ---- out = 3x3 conv n2 (y1) + 1x1 conv r (x) ----
#pragma unroll
    for (int k = 0; k < 2; ++k) {
        const int idx = tid + k * 256;
        const int py = idx / TW, px = idx % TW;
        const int gy = oy + py, gx = ox + px;
        float s[DD];
#pragma unroll
        for (int o = 0; o < DD; ++o) s[o] = b_n2[o] + b_r[o];
#pragma unroll
        for (int i = 0; i < DD; ++i)
#pragma unroll
            for (int dy = 0; dy < 3; ++dy)
#pragma unroll
                for (int dx = 0; dx < 3; ++dx) {
                    const float a = y1b[i][py + dy][px + dx];
#pragma unroll
                    for (int o = 0; o < DD; ++o)
                        s[o] += a * w_n2[o * 36 + i * 9 + dy * 3 + dx];
                }
#pragma unroll
        for (int c = 0; c < CIN; ++c) {
            const float xv = xa[c][py + 2][px + 2];
#pragma unroll
            for (int o = 0; o < DD; ++o) s[o] += xv * w_r[o * CIN + c];
        }
#pragma unroll
        for (int o = 0; o < DD; ++o)
            out[(((size_t)n * DD + o) * HH + gy) * WW + gx] = s[o];
    }
}

extern "C" void kernel_launch(void* const* d_in, const int* in_sizes, int n_in,
                              void* d_out, int out_size, void* d_ws, size_t ws_size,
                              hipStream_t stream) {
    const float* x      = (const float*)d_in[0];
    const float* w_down = (const float*)d_in[1];
    const float* b_down = (const float*)d_in[2];
    const float* w_e1   = (const float*)d_in[3];
    const float* b_e1   = (const float*)d_in[4];
    const float* w_e2   = (const float*)d_in[5];
    const float* b_e2   = (const float*)d_in[6];
    const float* w_up   = (const float*)d_in[7];
    const float* b_up   = (const float*)d_in[8];
    const float* w_n1   = (const float*)d_in[9];
    const float* b_n1   = (const float*)d_in[10];
    const float* w_n2   = (const float*)d_in[11];
    const float* b_n2   = (const float*)d_in[12];
    const float* w_r    = (const float*)d_in[13];
    const float* b_r    = (const float*)d_in[14];
    float* out = (float*)d_out;

    float* A   = (float*)d_ws;                    // EE*HH*WW floats (1 MiB)
    float* Aup = (float*)d_ws + EE * HH * WW;     // EE*HH*WW floats (1 MiB)

    // zero accumulator A
    zero_kernel<<<dim3(256), dim3(256), 0, stream>>>(A);

    // pass 1: edge CNN + sum over cells
    edge_kernel<<<dim3(WW / TW, HH / TH, NCELL / NCG), dim3(256), 0, stream>>>(
        x, w_down, b_down, w_e1, b_e1, w_e2, b_e2, A);

    // pass 2: 1x1 up conv on A
    up_kernel<<<dim3((HH * WW) / 256), dim3(256), 0, stream>>>(A, w_up, b_up, Aup);

    // pass 3: node CNN + residual
    node_kernel<<<dim3(WW / TW, HH / TH, NCELL), dim3(256), 0, stream>>>(
        x, Aup, w_n1, b_n1, w_n2, b_n2, w_r, b_r, out);
}